// Round 1
// baseline (219.676 us; speedup 1.0000x reference)
//
#include <hip/hip_runtime.h>

// Problem: AnchorPositionalEncoding
//   adj: [16384, 16384] f32, anchor_emb: [64, 128] f32
//   deg = rowsum(adj); nrm = ||deg|| + 1e-6
//   sim[i,a] = deg[i]*deg[a]/nrm; w = softmax_a(sim); out = w @ anchor_emb  -> [16384, 128] f32

constexpr int N_NODES = 16384;
constexpr int N_ANCH  = 64;
constexpr int HID     = 128;

// ---------------- Kernel 1: row sums (the 1.07 GB streaming pass) ----------------
__global__ __launch_bounds__(256) void rowsum_kernel(const float* __restrict__ adj,
                                                     float* __restrict__ deg) {
    const int row  = blockIdx.x;
    const int t    = threadIdx.x;
    const float4* __restrict__ p =
        reinterpret_cast<const float4*>(adj) + (size_t)row * (N_NODES / 4);

    float s = 0.0f;
#pragma unroll
    for (int i = 0; i < (N_NODES / 4) / 256; ++i) {   // 16 float4 loads / thread
        float4 v = p[t + i * 256];
        s += (v.x + v.y) + (v.z + v.w);
    }
    // wave(64) butterfly
#pragma unroll
    for (int off = 32; off > 0; off >>= 1) s += __shfl_down(s, off, 64);

    __shared__ float partial[4];
    const int lane = t & 63, wid = t >> 6;
    if (lane == 0) partial[wid] = s;
    __syncthreads();
    if (t == 0) deg[row] = (partial[0] + partial[1]) + (partial[2] + partial[3]);
}

// ---------------- Kernel 2: nrm = sqrt(sum(deg^2)) + 1e-6 ----------------
__global__ __launch_bounds__(1024) void norm_kernel(const float* __restrict__ deg,
                                                    float* __restrict__ nrm) {
    const int t = threadIdx.x;
    float s = 0.0f;
    for (int i = t; i < N_NODES; i += 1024) {
        float d = deg[i];
        s += d * d;
    }
#pragma unroll
    for (int off = 32; off > 0; off >>= 1) s += __shfl_down(s, off, 64);

    __shared__ float partial[16];
    const int lane = t & 63, wid = t >> 6;
    if (lane == 0) partial[wid] = s;
    __syncthreads();
    if (t == 0) {
        float tot = 0.0f;
#pragma unroll
        for (int i = 0; i < 16; ++i) tot += partial[i];
        *nrm = sqrtf(tot) + 1e-6f;
    }
}

// ---------------- Kernel 3: softmax(sim) @ anchor_emb ----------------
// 1024 blocks x 256 threads (4 waves). One wave per row, 4 rows per wave.
// Lane a holds sim[row][a]; softmax via shuffle butterfly; weights broadcast
// via __shfl; emb staged in LDS (stride-1 per-lane reads -> conflict-free).
__global__ __launch_bounds__(256) void out_kernel(const float* __restrict__ deg,
                                                  const float* __restrict__ nrm,
                                                  const float* __restrict__ emb,
                                                  float* __restrict__ out) {
    __shared__ float s_emb[N_ANCH * HID];   // 32 KiB
    __shared__ float s_dega[N_ANCH];

    const int t = threadIdx.x;
    for (int i = t; i < N_ANCH * HID; i += 256) s_emb[i] = emb[i];
    if (t < N_ANCH) s_dega[t] = deg[t];
    __syncthreads();

    const float inv_nrm = 1.0f / (*nrm);
    const int wid = t >> 6, lane = t & 63;
    const int rows_per_wave = N_NODES / (gridDim.x * 4);   // = 4
    const int row0 = (blockIdx.x * 4 + wid) * rows_per_wave;

    for (int r = 0; r < rows_per_wave; ++r) {
        const int row = row0 + r;
        const float d = deg[row];
        const float sim = d * s_dega[lane] * inv_nrm;

        // softmax over the 64 lanes
        float m = sim;
#pragma unroll
        for (int off = 32; off > 0; off >>= 1) m = fmaxf(m, __shfl_xor(m, off, 64));
        const float e = expf(sim - m);
        float ssum = e;
#pragma unroll
        for (int off = 32; off > 0; off >>= 1) ssum += __shfl_xor(ssum, off, 64);
        const float w = e / ssum;

        // out[row][lane], out[row][lane+64]
        float acc0 = 0.0f, acc1 = 0.0f;
#pragma unroll
        for (int a = 0; a < N_ANCH; ++a) {
            const float wa = __shfl(w, a, 64);
            acc0 = fmaf(wa, s_emb[a * HID + lane],      acc0);
            acc1 = fmaf(wa, s_emb[a * HID + 64 + lane], acc1);
        }
        out[(size_t)row * HID + lane]      = acc0;
        out[(size_t)row * HID + 64 + lane] = acc1;
    }
}

extern "C" void kernel_launch(void* const* d_in, const int* in_sizes, int n_in,
                              void* d_out, int out_size, void* d_ws, size_t ws_size,
                              hipStream_t stream) {
    const float* adj = (const float*)d_in[0];   // [16384, 16384] f32
    const float* emb = (const float*)d_in[1];   // [64, 128] f32
    float* out = (float*)d_out;                 // [16384, 128] f32

    float* deg = (float*)d_ws;                  // 16384 f32
    float* nrm = deg + N_NODES;                 // 1 f32

    rowsum_kernel<<<N_NODES, 256, 0, stream>>>(adj, deg);
    norm_kernel<<<1, 1024, 0, stream>>>(deg, nrm);
    out_kernel<<<1024, 256, 0, stream>>>(deg, nrm, emb, out);
}

// Round 2
// 180.664 us; speedup vs baseline: 1.2159x; 1.2159x over previous
//
#include <hip/hip_runtime.h>

// AnchorPositionalEncoding:
//   adj: [16384, 16384] f32, anchor_emb: [64, 128] f32
//   deg = rowsum(adj); nrm = ||deg||+1e-6; sim = deg*deg[:64]/nrm
//   out = softmax(sim) @ emb -> [16384, 128] f32
//
// K1: wave-per-row streaming rowsum (no per-row barriers; NT loads), emits
//     per-block sum-of-squares partials. K2 (norm) folded into K3 prologue.

constexpr int N_NODES = 16384;
constexpr int N_ANCH  = 64;
constexpr int HID     = 128;
constexpr int ROWS_PER_BLOCK = 8;                       // 2 rows per wave
constexpr int K1_BLOCKS = N_NODES / ROWS_PER_BLOCK;     // 2048
constexpr int K3_BLOCKS = 1024;                         // 4 waves x 4 rows each

typedef float f4 __attribute__((ext_vector_type(4)));

// ---------------- K1: row sums + ssq partials ----------------
__global__ __launch_bounds__(256) void rowsum_kernel(const float* __restrict__ adj,
                                                     float* __restrict__ deg,
                                                     float* __restrict__ ssq_part) {
    const int t = threadIdx.x, lane = t & 63, wid = t >> 6;
    const int row0 = blockIdx.x * ROWS_PER_BLOCK + wid * 2;
    float ssq = 0.0f;

    for (int r = 0; r < 2; ++r) {
        const int row = row0 + r;
        const f4* __restrict__ p =
            reinterpret_cast<const f4*>(adj) + (size_t)row * (N_NODES / 4) + lane;
        float s = 0.0f;
        for (int c = 0; c < 4; ++c) {              // 4 chunks x 16 loads in flight
            f4 v[16];                               // static-indexed -> registers
#pragma unroll
            for (int i = 0; i < 16; ++i)
                v[i] = __builtin_nontemporal_load(p + c * 1024 + i * 64);
#pragma unroll
            for (int i = 0; i < 16; ++i)
                s += (v[i].x + v[i].y) + (v[i].z + v[i].w);
        }
#pragma unroll
        for (int off = 32; off > 0; off >>= 1) s += __shfl_down(s, off, 64);
        if (lane == 0) { deg[row] = s; ssq = fmaf(s, s, ssq); }
    }

    __shared__ float sp[4];
    if (lane == 0) sp[wid] = ssq;
    __syncthreads();
    if (t == 0) ssq_part[blockIdx.x] = (sp[0] + sp[1]) + (sp[2] + sp[3]);
}

// ---------------- K3: norm + softmax(sim) @ emb ----------------
__global__ __launch_bounds__(256) void out_kernel(const float* __restrict__ deg,
                                                  const float* __restrict__ ssq_part,
                                                  const float* __restrict__ emb,
                                                  float* __restrict__ out) {
    __shared__ float s_emb[N_ANCH * HID];   // 32 KiB
    __shared__ float s_w[4][N_ANCH];
    __shared__ float s_red[4];
    __shared__ float s_inv;

    const int t = threadIdx.x, lane = t & 63, wid = t >> 6;

    // --- norm from 2048 partials (fixed tree -> deterministic) ---
    float ss = 0.0f;
#pragma unroll
    for (int i = 0; i < K1_BLOCKS / 256; ++i) ss += ssq_part[t + i * 256];
#pragma unroll
    for (int off = 32; off > 0; off >>= 1) ss += __shfl_down(ss, off, 64);
    if (lane == 0) s_red[wid] = ss;

    // --- stage emb (float4, coalesced) ---
    for (int i = t; i < N_ANCH * HID / 4; i += 256)
        reinterpret_cast<f4*>(s_emb)[i] = reinterpret_cast<const f4*>(emb)[i];
    __syncthreads();
    if (t == 0)
        s_inv = 1.0f / (sqrtf((s_red[0] + s_red[1]) + (s_red[2] + s_red[3])) + 1e-6f);
    __syncthreads();
    const float inv_nrm = s_inv;

    // --- per-lane emb columns in registers (128 VGPRs, static unroll) ---
    float e0[N_ANCH], e1[N_ANCH];
#pragma unroll
    for (int a = 0; a < N_ANCH; ++a) {
        e0[a] = s_emb[a * HID + lane];          // bank = lane%32 -> 2-way, free
        e1[a] = s_emb[a * HID + 64 + lane];
    }

    const float da = deg[lane] * inv_nrm;       // lane = anchor index
    const int row0 = (blockIdx.x * 4 + wid) * 4;

    for (int r = 0; r < 4; ++r) {
        const int row = row0 + r;
        const float sim = deg[row] * da;

        float m = sim;
#pragma unroll
        for (int off = 32; off > 0; off >>= 1) m = fmaxf(m, __shfl_xor(m, off, 64));
        const float e = __expf(sim - m);
        float sum = e;
#pragma unroll
        for (int off = 32; off > 0; off >>= 1) sum += __shfl_xor(sum, off, 64);
        s_w[wid][lane] = e / sum;               // wave-local; lgkmcnt orders r/w

        float acc0 = 0.0f, acc1 = 0.0f;
#pragma unroll
        for (int a4 = 0; a4 < N_ANCH; a4 += 4) {
            f4 w4 = *reinterpret_cast<const f4*>(&s_w[wid][a4]);  // same addr: broadcast
            acc0 = fmaf(w4.x, e0[a4 + 0], acc0); acc1 = fmaf(w4.x, e1[a4 + 0], acc1);
            acc0 = fmaf(w4.y, e0[a4 + 1], acc0); acc1 = fmaf(w4.y, e1[a4 + 1], acc1);
            acc0 = fmaf(w4.z, e0[a4 + 2], acc0); acc1 = fmaf(w4.z, e1[a4 + 2], acc1);
            acc0 = fmaf(w4.w, e0[a4 + 3], acc0); acc1 = fmaf(w4.w, e1[a4 + 3], acc1);
        }
        out[(size_t)row * HID + lane]      = acc0;
        out[(size_t)row * HID + 64 + lane] = acc1;
    }
}

extern "C" void kernel_launch(void* const* d_in, const int* in_sizes, int n_in,
                              void* d_out, int out_size, void* d_ws, size_t ws_size,
                              hipStream_t stream) {
    const float* adj = (const float*)d_in[0];   // [16384, 16384] f32
    const float* emb = (const float*)d_in[1];   // [64, 128] f32
    float* out = (float*)d_out;                 // [16384, 128] f32

    float* deg      = (float*)d_ws;             // 16384 f32
    float* ssq_part = deg + N_NODES;            // 2048 f32

    rowsum_kernel<<<K1_BLOCKS, 256, 0, stream>>>(adj, deg, ssq_part);
    out_kernel<<<K3_BLOCKS, 256, 0, stream>>>(deg, ssq_part, emb, out);
}